// Round 3
// baseline (3120.495 us; speedup 1.0000x reference)
//
#include <hip/hip_runtime.h>

typedef _Float16 f16;
typedef __attribute__((ext_vector_type(8))) _Float16 f16x8;
typedef __attribute__((ext_vector_type(4))) _Float16 f16x4;
typedef __attribute__((ext_vector_type(4))) float f32x4;

#define T_STEPS 784
#define HDIM    512
#define COUT    10

// W_rec f32 -> fp16, frag-major: frag (w,n,kk) = 64 lanes x 8 f16 (1 KB):
//   Wf[(((w*4+n)*16+kk)*64 + lane)*8 + j] = W_rec[w*64+n*16+(lane&15)][kk*32+(lane>>4)*8+j]
__global__ void cvt_w(const float* __restrict__ W, f16* __restrict__ Wf) {
    const int c  = blockIdx.x * 256 + threadIdx.x;
    const int l  = c & 63;
    const int kk = (c >> 6) & 15;
    const int n  = (c >> 10) & 3;
    const int w  = c >> 12;
    const int row = w * 64 + n * 16 + (l & 15);
    const int col = kk * 32 + (l >> 4) * 8;
    const float* s = W + row * HDIM + col;
    f16* d = Wf + (size_t)c * 8;
#pragma unroll
    for (int j = 0; j < 8; ++j) d[j] = (f16)s[j];
}

// xt[t][b] = x[b][perm[t]]  (makes the per-step x load a coalesced induction)
__global__ void permute_x(const float* __restrict__ x, const int* __restrict__ perm,
                          float* __restrict__ xt) {
    const int i = blockIdx.x * 256 + threadIdx.x;   // over 784*1024
    const int t = i >> 10, b = i & 1023;
    xt[i] = x[b * T_STEPS + perm[t]];
}

// 64 WGs x 512 thr (8 waves, 2/SIMD). WG owns 16 batch rows, all 512 cols.
// A = W rows (16 out-cols/tile), B = h (16 batch cols). kk 0..5 resident in
// VGPRs (96 regs); kk 6..15 streamed from L2 via staggered 2-slice buffers.
// h in LDS fp16, double-buffered, XOR-swizzled (byte ^= (row&7)<<4).
template<int USE_XT>
__global__ __launch_bounds__(512, 2)
void rnn_main(const float* __restrict__ x, const float* __restrict__ W_in,
              const f16* __restrict__ Wf, const float* __restrict__ W_out,
              const float* __restrict__ b_out, const int* __restrict__ perm,
              const float* __restrict__ xt, float* __restrict__ out)
{
    __shared__ __align__(16) char hb[32768];   // 2 x (16 rows x 1024 B)
    const int tid = threadIdx.x;
    const int w   = tid >> 6;
    const int lane = tid & 63;
    const int b   = lane & 15;
    const int lhi = lane >> 4;
    const int g   = b & 7;
    const int b0  = blockIdx.x * 16;

    for (int i = tid; i < 4096; i += 512) ((int*)hb)[i] = 0;  // zero buf0

    const f16* wb = Wf + (size_t)w * 64 * 512 + lane * 8;

    // resident W: kk 0..5 (96 VGPRs)
    f16x8 wr[24];
#pragma unroll
    for (int kk = 0; kk < 6; ++kk)
#pragma unroll
        for (int n = 0; n < 4; ++n)
            wr[kk * 4 + n] = *(const f16x8*)(wb + (n * 16 + kk) * 512);

    f16x4 win[4];
#pragma unroll
    for (int n = 0; n < 4; ++n)
#pragma unroll
        for (int r = 0; r < 4; ++r)
            win[n][r] = (f16)W_in[w * 64 + n * 16 + lhi * 4 + r];

    // LDS read bases: addr(kk) = (kk&1 ? Lo : Le) + (kk>>1)*128
    const int P  = (lhi ^ (g & 3)) << 4;
    const int Le = b * 1024 + ((g >> 2) << 6) + P;
    const int Lo = b * 1024 + ((1 ^ (g >> 2)) << 6) + P;
    // LDS write addrs (8B per n-tile)
    int wA[4];
#pragma unroll
    for (int n = 0; n < 4; ++n)
        wA[n] = b * 1024 + ((w * 128 + n * 32 + lhi * 8) ^ (g << 4));

    __syncthreads();

    int cur = 0;
#pragma unroll 1
    for (int t = 0; t < T_STEPS; ++t) {
        const char* rp = hb + cur;

        // stream issue: s0={6,7}, s1={8,9} now
        f16x8 s0[8], s1[8], s2[8], s3[8], s4[8];
#pragma unroll
        for (int n = 0; n < 4; ++n) {
            s0[n]     = *(const f16x8*)(wb + (n * 16 + 6) * 512);
            s0[4 + n] = *(const f16x8*)(wb + (n * 16 + 7) * 512);
        }
#pragma unroll
        for (int n = 0; n < 4; ++n) {
            s1[n]     = *(const f16x8*)(wb + (n * 16 + 8) * 512);
            s1[4 + n] = *(const f16x8*)(wb + (n * 16 + 9) * 512);
        }

        float xv;
        if (USE_XT) {
            xv = xt[t * 1024 + b0 + b];           // induction address, coalesced
        } else {
            const int pt = perm[t];
            xv = x[(size_t)(b0 + b) * T_STEPS + pt];
        }

        f32x4 acc[4];
#pragma unroll
        for (int n = 0; n < 4; ++n) acc[n] = (f32x4){0.f, 0.f, 0.f, 0.f};

        // resident kk 0..5
#pragma unroll
        for (int kk = 0; kk < 6; ++kk) {
            if (kk == 4) {
#pragma unroll
                for (int n = 0; n < 4; ++n) {      // s2 = {10,11}
                    s2[n]     = *(const f16x8*)(wb + (n * 16 + 10) * 512);
                    s2[4 + n] = *(const f16x8*)(wb + (n * 16 + 11) * 512);
                }
            }
            const f16x8 bh = *(const f16x8*)(rp + ((kk & 1) ? Lo : Le) + (kk >> 1) * 128);
#pragma unroll
            for (int n = 0; n < 4; ++n)
                acc[n] = __builtin_amdgcn_mfma_f32_16x16x32_f16(wr[kk * 4 + n], bh, acc[n], 0, 0, 0);
        }
        // kk 6,7 from s0
#pragma unroll
        for (int kk = 6; kk < 8; ++kk) {
            const f16x8 bh = *(const f16x8*)(rp + ((kk & 1) ? Lo : Le) + (kk >> 1) * 128);
#pragma unroll
            for (int n = 0; n < 4; ++n)
                acc[n] = __builtin_amdgcn_mfma_f32_16x16x32_f16(s0[(kk - 6) * 4 + n], bh, acc[n], 0, 0, 0);
        }
#pragma unroll
        for (int n = 0; n < 4; ++n) {              // s3 = {12,13}
            s3[n]     = *(const f16x8*)(wb + (n * 16 + 12) * 512);
            s3[4 + n] = *(const f16x8*)(wb + (n * 16 + 13) * 512);
        }
        // kk 8,9 from s1
#pragma unroll
        for (int kk = 8; kk < 10; ++kk) {
            const f16x8 bh = *(const f16x8*)(rp + ((kk & 1) ? Lo : Le) + (kk >> 1) * 128);
#pragma unroll
            for (int n = 0; n < 4; ++n)
                acc[n] = __builtin_amdgcn_mfma_f32_16x16x32_f16(s1[(kk - 8) * 4 + n], bh, acc[n], 0, 0, 0);
        }
#pragma unroll
        for (int n = 0; n < 4; ++n) {              // s4 = {14,15}
            s4[n]     = *(const f16x8*)(wb + (n * 16 + 14) * 512);
            s4[4 + n] = *(const f16x8*)(wb + (n * 16 + 15) * 512);
        }
        // kk 10..15 from s2,s3,s4
#pragma unroll
        for (int kk = 10; kk < 12; ++kk) {
            const f16x8 bh = *(const f16x8*)(rp + ((kk & 1) ? Lo : Le) + (kk >> 1) * 128);
#pragma unroll
            for (int n = 0; n < 4; ++n)
                acc[n] = __builtin_amdgcn_mfma_f32_16x16x32_f16(s2[(kk - 10) * 4 + n], bh, acc[n], 0, 0, 0);
        }
#pragma unroll
        for (int kk = 12; kk < 14; ++kk) {
            const f16x8 bh = *(const f16x8*)(rp + ((kk & 1) ? Lo : Le) + (kk >> 1) * 128);
#pragma unroll
            for (int n = 0; n < 4; ++n)
                acc[n] = __builtin_amdgcn_mfma_f32_16x16x32_f16(s3[(kk - 12) * 4 + n], bh, acc[n], 0, 0, 0);
        }
#pragma unroll
        for (int kk = 14; kk < 16; ++kk) {
            const f16x8 bh = *(const f16x8*)(rp + ((kk & 1) ? Lo : Le) + (kk >> 1) * 128);
#pragma unroll
            for (int n = 0; n < 4; ++n)
                acc[n] = __builtin_amdgcn_mfma_f32_16x16x32_f16(s4[(kk - 14) * 4 + n], bh, acc[n], 0, 0, 0);
        }

        // epilogue: inject + relu, 4 x 8B swizzled stores
        char* wp_ = hb + (cur ^ 16384);
#pragma unroll
        for (int n = 0; n < 4; ++n) {
            f16x4 hv;
#pragma unroll
            for (int r = 0; r < 4; ++r) {
                float v = acc[n][r] + xv * (float)win[n][r];
                hv[r] = (f16)fmaxf(v, 0.f);
            }
            *(f16x4*)(wp_ + wA[n]) = hv;
        }
        __syncthreads();
        cur ^= 16384;
    }

    // projection: out[b,c] = h_last[b,:] . W_out[c,:] + b_out[c]
    if (tid < 16 * COUT) {
        const int r = tid / COUT, c = tid % COUT;
        const char* hr = hb + cur + r * 1024;
        const int gr = (r & 7) << 4;
        float s_ = b_out[c];
        const float* wo = W_out + c * HDIM;
#pragma unroll 4
        for (int j0 = 0; j0 < HDIM; j0 += 8) {
            f16x8 hv = *(const f16x8*)(hr + ((j0 * 2) ^ gr));
#pragma unroll
            for (int jj = 0; jj < 8; ++jj)
                s_ += (float)hv[jj] * wo[j0 + jj];
        }
        out[(b0 + r) * COUT + c] = s_;
    }
}

extern "C" void kernel_launch(void* const* d_in, const int* in_sizes, int n_in,
                              void* d_out, int out_size, void* d_ws, size_t ws_size,
                              hipStream_t stream)
{
    (void)in_sizes; (void)n_in; (void)out_size;
    const float* x     = (const float*)d_in[0];
    const float* W_in  = (const float*)d_in[1];
    const float* W_rec = (const float*)d_in[2];
    const float* W_out = (const float*)d_in[3];
    const float* b_out = (const float*)d_in[4];
    const int*   perm  = (const int*)d_in[5];
    float* out = (float*)d_out;

    f16*   Wf = (f16*)d_ws;                                  // 512 KB
    float* xt = (float*)((char*)d_ws + 512 * 1024);          // 3.2 MB
    const size_t need = 512 * 1024 + (size_t)T_STEPS * 1024 * 4;

    cvt_w<<<dim3(128), dim3(256), 0, stream>>>(W_rec, Wf);
    if (ws_size >= need) {
        permute_x<<<dim3(T_STEPS * 1024 / 256), dim3(256), 0, stream>>>(x, perm, xt);
        rnn_main<1><<<dim3(64), dim3(512), 0, stream>>>(x, W_in, Wf, W_out, b_out, perm, xt, out);
    } else {
        rnn_main<0><<<dim3(64), dim3(512), 0, stream>>>(x, W_in, Wf, W_out, b_out, perm, nullptr, out);
    }
}

// Round 4
// 3063.822 us; speedup vs baseline: 1.0185x; 1.0185x over previous
//
#include <hip/hip_runtime.h>

typedef _Float16 f16;
typedef __attribute__((ext_vector_type(8))) _Float16 f16x8;
typedef __attribute__((ext_vector_type(4))) _Float16 f16x4;
typedef __attribute__((ext_vector_type(4))) float f32x4;

#define T_STEPS 784
#define HDIM    512
#define COUT    10

#define MFMA16(a, b, c) __builtin_amdgcn_mfma_f32_16x16x32_f16((a), (b), (c), 0, 0, 0)
#define LGKM_BARRIER() asm volatile("s_waitcnt lgkmcnt(0)\n\ts_barrier" ::: "memory")

// W_rec f32 -> fp16, frag-major: frag (w,n,kk) = 64 lanes x 8 f16 (1 KB):
//   Wf[(((w*4+n)*16+kk)*64 + lane)*8 + j] = W_rec[w*64+n*16+(lane&15)][kk*32+(lane>>4)*8+j]
__global__ void cvt_w(const float* __restrict__ W, f16* __restrict__ Wf) {
    const int c  = blockIdx.x * 256 + threadIdx.x;
    const int l  = c & 63;
    const int kk = (c >> 6) & 15;
    const int n  = (c >> 10) & 3;
    const int w  = c >> 12;
    const int row = w * 64 + n * 16 + (l & 15);
    const int col = kk * 32 + (l >> 4) * 8;
    const float* s = W + row * HDIM + col;
    f16* d = Wf + (size_t)c * 8;
#pragma unroll
    for (int j = 0; j < 8; ++j) d[j] = (f16)s[j];
}

// xt[t][b] = x[b][perm[t]]
__global__ void permute_x(const float* __restrict__ x, const int* __restrict__ perm,
                          float* __restrict__ xt) {
    const int i = blockIdx.x * 256 + threadIdx.x;
    const int t = i >> 10, b = i & 1023;
    xt[i] = x[b * T_STEPS + perm[t]];
}

// 64 WGs x 512 thr, PINNED 2 waves/SIMD (256-VGPR budget). WG owns 16 batch
// rows. A = W rows, B = h. kk 0..8 resident in VGPRs (144 regs, pinned by asm
// opacity fences); kk 9..15 streamed from L2 per step via rolling pair
// buffers; the (9,10) pair prefetches across an lgkm-only barrier.
__global__ __launch_bounds__(512)
__attribute__((amdgpu_waves_per_eu(2, 2)))
void rnn_main(const float* __restrict__ W_in, const f16* __restrict__ Wf,
              const float* __restrict__ W_out, const float* __restrict__ b_out,
              const float* __restrict__ xt, float* __restrict__ out)
{
    __shared__ __align__(16) char hb[32768];   // 2 x (16 rows x 1024 B)
    const int tid = threadIdx.x;
    const int w   = tid >> 6;
    const int lane = tid & 63;
    const int b   = lane & 15;
    const int lhi = lane >> 4;
    const int g   = b & 7;
    const int b0  = blockIdx.x * 16;

    for (int i = tid; i < 4096; i += 512) ((int*)hb)[i] = 0;  // zero buf0

    const f16* wb = Wf + (size_t)w * 64 * 512 + lane * 8;
#define LDW(kk, n) (*(const f16x8*)(wb + ((n) * 16 + (kk)) * 512))

    // resident W: kk 0..8 (144 VGPRs), pinned via opacity fences
    f16x8 wr[36];
#pragma unroll
    for (int kk = 0; kk < 9; ++kk)
#pragma unroll
        for (int n = 0; n < 4; ++n)
            wr[kk * 4 + n] = LDW(kk, n);
#pragma unroll
    for (int i = 0; i < 36; ++i)
        asm volatile("" : "+v"(wr[i]));

    f16x4 win[4];
#pragma unroll
    for (int n = 0; n < 4; ++n)
#pragma unroll
        for (int r = 0; r < 4; ++r)
            win[n][r] = (f16)W_in[w * 64 + n * 16 + lhi * 4 + r];

    // LDS read bases: addr(kk) = (kk&1 ? Lo : Le) + (kk>>1)*128
    const int P  = (lhi ^ (g & 3)) << 4;
    const int Le = b * 1024 + ((g >> 2) << 6) + P;
    const int Lo = b * 1024 + ((1 ^ (g >> 2)) << 6) + P;
    int wA[4];
#pragma unroll
    for (int n = 0; n < 4; ++n)
        wA[n] = b * 1024 + ((w * 128 + n * 32 + lhi * 8) ^ (g << 4));

    __syncthreads();

    // prologue prefetch: pair P = kk {9,10}
    f16x8 p[8];
#pragma unroll
    for (int n = 0; n < 4; ++n) { p[n] = LDW(9, n); p[4 + n] = LDW(10, n); }

#define RES_KK(kk)                                                              \
    {                                                                           \
        const f16x8 bh = *(const f16x8*)(rp + (((kk) & 1) ? Lo : Le) + ((kk) >> 1) * 128); \
        acc[0] = MFMA16(wr[(kk) * 4 + 0], bh, acc[0]);                          \
        acc[1] = MFMA16(wr[(kk) * 4 + 1], bh, acc[1]);                          \
        acc[2] = MFMA16(wr[(kk) * 4 + 2], bh, acc[2]);                          \
        acc[3] = MFMA16(wr[(kk) * 4 + 3], bh, acc[3]);                          \
    }
#define STR_KK(kk, buf, o)                                                      \
    {                                                                           \
        const f16x8 bh = *(const f16x8*)(rp + (((kk) & 1) ? Lo : Le) + ((kk) >> 1) * 128); \
        acc[0] = MFMA16((buf)[(o) + 0], bh, acc[0]);                            \
        acc[1] = MFMA16((buf)[(o) + 1], bh, acc[1]);                            \
        acc[2] = MFMA16((buf)[(o) + 2], bh, acc[2]);                            \
        acc[3] = MFMA16((buf)[(o) + 3], bh, acc[3]);                            \
    }

    int cur = 0;
#pragma unroll 1
    for (int t = 0; t < T_STEPS; ++t) {
        const char* rp = hb + cur;
        const float xv = xt[t * 1024 + b0 + b];

        f32x4 acc[4];
#pragma unroll
        for (int n = 0; n < 4; ++n) acc[n] = (f32x4){0.f, 0.f, 0.f, 0.f};

        f16x8 q[8], r[8], s4[4];

        RES_KK(0)
        RES_KK(1)
        RES_KK(2)
        // issue Q = kk {11,12}
#pragma unroll
        for (int n = 0; n < 4; ++n) { q[n] = LDW(11, n); q[4 + n] = LDW(12, n); }
        RES_KK(3)
        RES_KK(4)
        RES_KK(5)
        RES_KK(6)
        RES_KK(7)
        RES_KK(8)
        // issue R = kk {13,14} (just before P is consumed/freed)
#pragma unroll
        for (int n = 0; n < 4; ++n) { r[n] = LDW(13, n); r[4 + n] = LDW(14, n); }
        // consume P
        STR_KK(9, p, 0)
        STR_KK(10, p, 4)
        // issue S = kk {15}
#pragma unroll
        for (int n = 0; n < 4; ++n) s4[n] = LDW(15, n);
        // consume Q, R, S
        STR_KK(11, q, 0)
        STR_KK(12, q, 4)
        STR_KK(13, r, 0)
        STR_KK(14, r, 4)
        STR_KK(15, s4, 0)

        // epilogue: inject + relu, 4 x 8B swizzled stores
        char* wp_ = hb + (cur ^ 16384);
#pragma unroll
        for (int n = 0; n < 4; ++n) {
            f16x4 hv;
#pragma unroll
            for (int rr = 0; rr < 4; ++rr) {
                float v = acc[n][rr] + xv * (float)win[n][rr];
                hv[rr] = (f16)fmaxf(v, 0.f);
            }
            *(f16x4*)(wp_ + wA[n]) = hv;
        }

        // prefetch next step's P = kk {9,10}; stays in flight across barrier
#pragma unroll
        for (int n = 0; n < 4; ++n) { p[n] = LDW(9, n); p[4 + n] = LDW(10, n); }

        LGKM_BARRIER();
        cur ^= 16384;
    }

    // projection: out[b,c] = h_last[b,:] . W_out[c,:] + b_out[c]
    if (tid < 16 * COUT) {
        const int rr = tid / COUT, c = tid % COUT;
        const char* hr = hb + cur + rr * 1024;
        const int gr = (rr & 7) << 4;
        float s_ = b_out[c];
        const float* wo = W_out + c * HDIM;
#pragma unroll 4
        for (int j0 = 0; j0 < HDIM; j0 += 8) {
            f16x8 hv = *(const f16x8*)(hr + ((j0 * 2) ^ gr));
#pragma unroll
            for (int jj = 0; jj < 8; ++jj)
                s_ += (float)hv[jj] * wo[j0 + jj];
        }
        out[(b0 + rr) * COUT + c] = s_;
    }
}

extern "C" void kernel_launch(void* const* d_in, const int* in_sizes, int n_in,
                              void* d_out, int out_size, void* d_ws, size_t ws_size,
                              hipStream_t stream)
{
    (void)in_sizes; (void)n_in; (void)out_size; (void)ws_size;
    const float* x     = (const float*)d_in[0];
    const float* W_in  = (const float*)d_in[1];
    const float* W_rec = (const float*)d_in[2];
    const float* W_out = (const float*)d_in[3];
    const float* b_out = (const float*)d_in[4];
    const int*   perm  = (const int*)d_in[5];
    float* out = (float*)d_out;

    f16*   Wf = (f16*)d_ws;                                  // 512 KB
    float* xt = (float*)((char*)d_ws + 512 * 1024);          // 3.2 MB

    cvt_w<<<dim3(128), dim3(256), 0, stream>>>(W_rec, Wf);
    permute_x<<<dim3(T_STEPS * 1024 / 256), dim3(256), 0, stream>>>(x, perm, xt);
    rnn_main<<<dim3(64), dim3(512), 0, stream>>>(W_in, Wf, W_out, b_out, xt, out);
}

// Round 6
// 2849.383 us; speedup vs baseline: 1.0951x; 1.0753x over previous
//
#include <hip/hip_runtime.h>

typedef _Float16 f16;
typedef __attribute__((ext_vector_type(8))) _Float16 f16x8;
typedef __attribute__((ext_vector_type(4))) _Float16 f16x4;
typedef __attribute__((ext_vector_type(4))) float f32x4;

#define T_STEPS 784
#define HDIM    512
#define COUT    10

#define MFMA16(a, b, c) __builtin_amdgcn_mfma_f32_16x16x32_f16((a), (b), (c), 0, 0, 0)

// W_rec f32 -> fp16, frag-major: frag (w,n,kk) = 64 lanes x 8 f16 (1 KB):
//   Wf[(((w*4+n)*16+kk)*64 + lane)*8 + j] = W_rec[w*64+n*16+(lane&15)][kk*32+(lane>>4)*8+j]
__global__ void cvt_w(const float* __restrict__ W, f16* __restrict__ Wf) {
    const int c  = blockIdx.x * 256 + threadIdx.x;
    const int l  = c & 63;
    const int kk = (c >> 6) & 15;
    const int n  = (c >> 10) & 3;
    const int w  = c >> 12;
    const int row = w * 64 + n * 16 + (l & 15);
    const int col = kk * 32 + (l >> 4) * 8;
    const float* s = W + row * HDIM + col;
    f16* d = Wf + (size_t)c * 8;
#pragma unroll
    for (int j = 0; j < 8; ++j) d[j] = (f16)s[j];
}

// xt[t][b] = x[b][perm[t]]
__global__ void permute_x(const float* __restrict__ x, const int* __restrict__ perm,
                          float* __restrict__ xt) {
    const int i = blockIdx.x * 256 + threadIdx.x;
    const int t = i >> 10, b = i & 1023;
    xt[i] = x[b * T_STEPS + perm[t]];
}

// 64 WGs x 512 thr (8 waves, 2/SIMD). WG owns 16 batch rows, all 512 outcols.
// NO resident W (fits 128 VGPRs by design). Per step each wave streams its
// 64 KB W slice through a 4-deep register ring (16 KB in flight), slice kk+4
// issued as slice kk is consumed; next step's slices 0..3 issue at kk=12..15
// and stay in flight across the lgkm-only barrier (vmcnt never drains).
// h lives in LDS in MFMA-B-frag-major layout: frag kk = 1 KB, lane-linear ->
// conflict-free ds_read_b128; epilogue = 4 contiguous ds_write_b64.
__global__ __launch_bounds__(512, 2)
void rnn_main(const float* __restrict__ W_in, const f16* __restrict__ Wf,
              const float* __restrict__ W_out, const float* __restrict__ b_out,
              const float* __restrict__ xt, float* __restrict__ out)
{
    __shared__ __align__(16) char hb[32768];   // 2 x 16 frags x 1 KB
    const int tid  = threadIdx.x;
    const int w    = tid >> 6;
    const int lane = tid & 63;
    const int b    = lane & 15;
    const int lhi  = lane >> 4;
    const int b0   = blockIdx.x * 16;

    for (int i = tid; i < 4096; i += 512) ((int*)hb)[i] = 0;  // h0 = 0 (buf0)

    const f16* wb = Wf + (size_t)w * 32768 + lane * 8;
#define LDW(kk, n) (*(const f16x8*)(wb + ((n) * 16 + (kk)) * 512))

    // W_in for this lane's 16 outcols: o = w*64 + n*16 + lhi*4 + r
    f16x4 win[4];
#pragma unroll
    for (int n = 0; n < 4; ++n)
#pragma unroll
        for (int r = 0; r < 4; ++r)
            win[n][r] = (f16)W_in[w * 64 + n * 16 + lhi * 4 + r];

    // LDS addresses.
    // read: frag kk at (buf + kk*1024 + lane*16) -- lane-linear, conflict-free
    char* const rb = hb + lane * 16;
    // write: element o = w*64+n*16+lhi*4+r, batch b ->
    //   frag 2w+(n>>1), sublane ((n&1)*2+(lhi>>1))<<4 | b, byte (lhi&1)*8 + r*2
    int wa[4];
#pragma unroll
    for (int n = 0; n < 4; ++n)
        wa[n] = (2 * w + (n >> 1)) * 1024
              + (((((n & 1) * 2 + (lhi >> 1)) << 4) | b) * 16)
              + (lhi & 1) * 8;

    __syncthreads();

    // preload slices 0..3 (ring slots are named -> all indices static)
    f16x8 r0[4], r1[4], r2[4], r3[4];
#pragma unroll
    for (int n = 0; n < 4; ++n) r0[n] = LDW(0, n);
#pragma unroll
    for (int n = 0; n < 4; ++n) r1[n] = LDW(1, n);
#pragma unroll
    for (int n = 0; n < 4; ++n) r2[n] = LDW(2, n);
#pragma unroll
    for (int n = 0; n < 4; ++n) r3[n] = LDW(3, n);

#define STEP_KK(kk, RING, nxt)                                      \
    {                                                               \
        const f16x8 bh = *(const f16x8*)(rp + (kk) * 1024);         \
        acc0 = MFMA16(RING[0], bh, acc0);                           \
        acc1 = MFMA16(RING[1], bh, acc1);                           \
        acc2 = MFMA16(RING[2], bh, acc2);                           \
        acc3 = MFMA16(RING[3], bh, acc3);                           \
        RING[0] = LDW(nxt, 0); RING[1] = LDW(nxt, 1);               \
        RING[2] = LDW(nxt, 2); RING[3] = LDW(nxt, 3);               \
    }

    int cur = 0;
#pragma unroll 1
    for (int t = 0; t < T_STEPS; ++t) {
        const float xv = xt[t * 1024 + b0 + b];
        const char* rp = rb + cur;
        char* wq = hb + (cur ^ 16384);

        f32x4 acc0 = {0.f, 0.f, 0.f, 0.f};
        f32x4 acc1 = {0.f, 0.f, 0.f, 0.f};
        f32x4 acc2 = {0.f, 0.f, 0.f, 0.f};
        f32x4 acc3 = {0.f, 0.f, 0.f, 0.f};

        STEP_KK(0,  r0, 4)   STEP_KK(1,  r1, 5)
        STEP_KK(2,  r2, 6)   STEP_KK(3,  r3, 7)
        STEP_KK(4,  r0, 8)   STEP_KK(5,  r1, 9)
        STEP_KK(6,  r2, 10)  STEP_KK(7,  r3, 11)
        STEP_KK(8,  r0, 12)  STEP_KK(9,  r1, 13)
        STEP_KK(10, r2, 14)  STEP_KK(11, r3, 15)
        STEP_KK(12, r0, 0)   STEP_KK(13, r1, 1)   // nxt = NEXT step's slices,
        STEP_KK(14, r2, 2)   STEP_KK(15, r3, 3)   // in flight across barrier

        // epilogue: inject + relu, 4 x contiguous 8B stores (conflict-free)
        {
            f16x4 hv;
            float v;
#define EPI(n, ACC)                                                  \
            v = ACC[0] + xv * (float)win[n][0]; hv[0] = (f16)fmaxf(v, 0.f); \
            v = ACC[1] + xv * (float)win[n][1]; hv[1] = (f16)fmaxf(v, 0.f); \
            v = ACC[2] + xv * (float)win[n][2]; hv[2] = (f16)fmaxf(v, 0.f); \
            v = ACC[3] + xv * (float)win[n][3]; hv[3] = (f16)fmaxf(v, 0.f); \
            *(f16x4*)(wq + wa[n]) = hv;
            EPI(0, acc0) EPI(1, acc1) EPI(2, acc2) EPI(3, acc3)
#undef EPI
        }

        // wait own LDS ops only; W prefetch (vmcnt) stays in flight
        asm volatile("s_waitcnt lgkmcnt(0)\n\ts_barrier" ::: "memory");
        cur ^= 16384;
    }

    // projection: out[b,c] = h_last[b,:] . W_out[c,:] + b_out[c]
    // h element (o, bb) lives at frag (o>>5), byte ((((o>>3)&3)<<4)|bb)*16 + (o&7)*2
    if (tid < 16 * COUT) {
        const int bb = tid / COUT, c = tid % COUT;
        const char* hr = hb + cur;
        float s_ = b_out[c];
        const float* wo = W_out + c * HDIM;
#pragma unroll 4
        for (int o0 = 0; o0 < HDIM; o0 += 8) {
            const int off = (o0 >> 5) * 1024 + (((((o0 >> 3) & 3) << 4) | bb) * 16);
            f16x8 hv = *(const f16x8*)(hr + off);
#pragma unroll
            for (int jj = 0; jj < 8; ++jj)
                s_ += (float)hv[jj] * wo[o0 + jj];
        }
        out[(b0 + bb) * COUT + c] = s_;
    }
}

extern "C" void kernel_launch(void* const* d_in, const int* in_sizes, int n_in,
                              void* d_out, int out_size, void* d_ws, size_t ws_size,
                              hipStream_t stream)
{
    (void)in_sizes; (void)n_in; (void)out_size; (void)ws_size;
    const float* x     = (const float*)d_in[0];
    const float* W_in  = (const float*)d_in[1];
    const float* W_rec = (const float*)d_in[2];
    const float* W_out = (const float*)d_in[3];
    const float* b_out = (const float*)d_in[4];
    const int*   perm  = (const int*)d_in[5];
    float* out = (float*)d_out;

    f16*   Wf = (f16*)d_ws;                           // 512 KB
    float* xt = (float*)((char*)d_ws + 512 * 1024);   // 3.2 MB

    cvt_w<<<dim3(128), dim3(256), 0, stream>>>(W_rec, Wf);
    permute_x<<<dim3(T_STEPS * 1024 / 256), dim3(256), 0, stream>>>(x, perm, xt);
    rnn_main<<<dim3(64), dim3(512), 0, stream>>>(W_in, Wf, W_out, b_out, xt, out);
}